// Round 4
// baseline (38.703 us; speedup 1.0000x reference)
//
#include <hip/hip_runtime.h>

#define B_    8
#define OXD   30
#define OYD   30
#define OZD   14
#define NLOC  (OXD*OYD*OZD)      // 12600
#define F_    16
#define T_    216                // 3*3*3*8
#define WPL   (T_*F_)            // 3456 weights per location
#define OZH   (OZD/2)            // 7
#define NBLK  (OXD*OYD*OZH)      // 6300

__global__ __launch_bounds__(128, 4)
void lc3d_kernel(const float* __restrict__ in, const float* __restrict__ wgt,
                 const float* __restrict__ bias, float* __restrict__ out) {
    // patch slab covers z in [oz0, oz0+3]: serves locations oz0 and oz0+1
    __shared__ float patch[B_ * 9 * 32];   // [b][ij][(z-oz0)*8+c] = 2304 fl, 9.2 KB
    __shared__ float red[2][2 * 128];      // per-loc cross-wave partials, 2 KB

    const int blk = blockIdx.x;
    const int ox  = blk / (OYD * OZH);
    const int rem = blk - ox * (OYD * OZH);
    const int oy  = rem / OZH;
    const int ozh = rem - oy * OZH;
    const int oz0 = 2 * ozh;
    const int loc0 = (ox * OYD + oy) * OZD + oz0;   // loc1 = loc0 + 1

    const int tid = threadIdx.x;
    const int fq  = tid & 3;            // f quadrant
    const int tg  = tid >> 2;           // 0..31 t-group
    const float* wloc = wgt + (size_t)loc0 * WPL;

    const float bi0 = bias[(size_t)loc0 * F_ + (tid & 15)];
    const float bi1 = bias[(size_t)(loc0 + 1) * F_ + (tid & 15)];

    // ---- issue ALL 14 weight float4 loads upfront: the two locations'
    // weights are contiguous (27.6 KB/block), latency hides under staging
    // and loc0 compute. 224 B/thread in flight.
    float4 w[14];
    #pragma unroll
    for (int l = 0; l < 2; ++l) {
        #pragma unroll
        for (int it = 0; it < 6; ++it)
            w[l * 7 + it] = *reinterpret_cast<const float4*>(
                wloc + l * WPL + (tg + 32 * it) * F_ + fq * 4);
        w[l * 7 + 6] = make_float4(0.f, 0.f, 0.f, 0.f);
        if (tg < 24)                    // 216 = 6*32 + 24
            w[l * 7 + 6] = *reinterpret_cast<const float4*>(
                wloc + l * WPL + (tg + 192) * F_ + fq * 4);
    }

    // ---- stage patch slab: 72 (b,ij) segments x 32 floats (4z*8c, contiguous
    // in memory since z,c are innermost) = 576 float4
    {
        const float4* in4 = reinterpret_cast<const float4*>(in);
        float4* patch4 = reinterpret_cast<float4*>(patch);
        #pragma unroll
        for (int r = 0; r < 5; ++r) {
            int idx = tid + 128 * r;    // 0..575
            if (r < 4 || tid < 64) {
                int seg = idx >> 3;     // 0..71 = b*9 + ij
                int off = idx & 7;
                int b   = seg / 9;
                int ij  = seg - b * 9;
                int i   = ij / 3;
                int j   = ij - i * 3;
                int g4  = (((b * 32 + ox + i) * 32 + (oy + j)) * 16 + oz0) * 2 + off;
                patch4[idx] = in4[g4];
            }
        }
    }
    __syncthreads();

    // ---- per-location compute (zoff = 0, then 8)
    #pragma unroll
    for (int l = 0; l < 2; ++l) {
        float a[32];
        #pragma unroll
        for (int e = 0; e < 32; ++e) a[e] = 0.f;

        #pragma unroll
        for (int it = 0; it < 7; ++it) {
            const int t  = tg + 32 * it;
            const int tc = (t < T_) ? t : 0;          // clamp; w=0 there
            const int vi = tc + (tc / 24) * 8 + l * 8; // [ij][z+k][c] flat index
            const float4 ww = w[l * 7 + it];
            #pragma unroll
            for (int b = 0; b < B_; ++b) {
                const float p = patch[b * 288 + vi];   // broadcast across fq
                a[b * 4 + 0] += p * ww.x;
                a[b * 4 + 1] += p * ww.y;
                a[b * 4 + 2] += p * ww.z;
                a[b * 4 + 3] += p * ww.w;
            }
        }

        // in-wave butterfly over the 16 in-wave t-groups, folding elements:
        // 16+8+4+2 = 30 shuffles -> 2 partials/lane
#define RSTEP(m, k)                                         \
        {                                                   \
            const bool hi = (tid & (m)) != 0;               \
            _Pragma("unroll")                               \
            for (int e = 0; e < (k); ++e) {                 \
                float v = hi ? a[e] : a[e + (k)];           \
                float r = __shfl_xor(v, (m), 64);           \
                a[e] = (hi ? a[e + (k)] : a[e]) + r;        \
            }                                               \
        }
        RSTEP(4, 16)
        RSTEP(8, 8)
        RSTEP(16, 4)
        RSTEP(32, 2)
#undef RSTEP

        const int eg = ((tid & 4) << 2) | (tid & 8) | ((tid & 16) >> 2) | ((tid & 32) >> 4);
        const int wv = tid >> 6;
        red[l][wv * 128 + (eg + 0) * 4 + fq] = a[0];
        red[l][wv * 128 + (eg + 1) * 4 + fq] = a[1];
        __syncthreads();

        {
            const int b   = tid >> 4;
            const int f   = tid & 15;
            const int e2  = ((b * 4 + (f & 3)) * 4) + (f >> 2);
            const float s = (l == 0 ? bi0 : bi1) + red[l][e2] + red[l][128 + e2];
            out[((size_t)b * NLOC + loc0 + l) * F_ + f] = s;
        }
        // no barrier needed here: next iteration writes red[1-..], a disjoint
        // buffer, and patch is read-only for the rest of the kernel
    }
}

extern "C" void kernel_launch(void* const* d_in, const int* in_sizes, int n_in,
                              void* d_out, int out_size, void* d_ws, size_t ws_size,
                              hipStream_t stream) {
    const float* in   = (const float*)d_in[0];
    const float* wgt  = (const float*)d_in[1];
    const float* bias = (const float*)d_in[2];
    float* out = (float*)d_out;
    lc3d_kernel<<<NBLK, 128, 0, stream>>>(in, wgt, bias, out);
}